// Round 14
// baseline (252.470 us; speedup 1.0000x reference)
//
#include <hip/hip_runtime.h>
#include <hip/hip_bf16.h>

#define N_NODES 8192
#define F_IN 256
#define F_OUT 128
#define NSTEP (N_NODES / 32)    // 256 K-steps of 32

typedef __attribute__((ext_vector_type(4))) float f32x4;
typedef __attribute__((ext_vector_type(8))) short bf16x8;
typedef __attribute__((ext_vector_type(4))) unsigned int u32x4;

static __device__ __forceinline__ short bfr(float x) {
    __hip_bfloat16 h = __float2bfloat16(x);   // RNE
    union { __hip_bfloat16 h; short s; } u; u.h = h;
    return u.s;
}

// Kernel 1: support^T[f][n] = sum_k X[n][k] * W[k][f]   (fp32 accum -> bf16)
__global__ __launch_bounds__(256) void support_kernel(
        const float* __restrict__ X, const float* __restrict__ W,
        unsigned short* __restrict__ supT) {
    __shared__ float Xs[32][68];
    __shared__ float Ws[64][128];
    const int t = threadIdx.x;
    const int n0 = blockIdx.x * 32;
    const int tc = t & 31;
    const int tr = t >> 5;
    float acc[4][4];
    #pragma unroll
    for (int i = 0; i < 4; ++i)
        #pragma unroll
        for (int j = 0; j < 4; ++j) acc[i][j] = 0.f;

    for (int k0 = 0; k0 < F_IN; k0 += 64) {
        __syncthreads();
        {
            const int r = t >> 3, kc = (t & 7) * 8;
            const float* src = X + (size_t)(n0 + r) * F_IN + k0 + kc;
            f32x4 v0 = *(const f32x4*)src;
            f32x4 v1 = *(const f32x4*)(src + 4);
            *(f32x4*)&Xs[r][kc]     = v0;
            *(f32x4*)&Xs[r][kc + 4] = v1;
        }
        {
            const int col = t & 127, kb = t >> 7;
            #pragma unroll
            for (int i = 0; i < 32; ++i) {
                const int k = kb + i * 2;
                Ws[k][col] = W[(size_t)(k0 + k) * F_OUT + col];
            }
        }
        __syncthreads();
        #pragma unroll 8
        for (int k = 0; k < 64; ++k) {
            const f32x4 b = *(const f32x4*)&Ws[k][tc * 4];
            float a[4];
            #pragma unroll
            for (int i = 0; i < 4; ++i) a[i] = Xs[tr * 4 + i][k];
            #pragma unroll
            for (int i = 0; i < 4; ++i) {
                acc[i][0] += a[i] * b.x; acc[i][1] += a[i] * b.y;
                acc[i][2] += a[i] * b.z; acc[i][3] += a[i] * b.w;
            }
        }
    }
    #pragma unroll
    for (int j = 0; j < 4; ++j) {
        const int col = tc * 4 + j;
        #pragma unroll
        for (int i = 0; i < 4; ++i) {
            supT[(size_t)col * N_NODES + n0 + tr * 4 + i] =
                (unsigned short)bfr(acc[i][j]);
        }
    }
}

// Kernel 2: out = adj @ support + bias. ZERO LDS, ZERO barriers, no split-K.
// 512 blocks x 256 thr (4 waves). Block = 16-row stripe; wave w = cols w*32.
// Both fragments loaded straight from global via asm global_load_dwordx4:
//   A: adj rows (HBM stream), fp32 -> v_cvt_pk_bf16_f32 in-reg.
//   B: supT [f][n] (2MB, L2-resident), bf16 k-contiguous.
// Depth-4 software pipeline with 4 NAMED register sets and a manual vmcnt
// ledger (4 loads/step, 16 in flight; steady WAIT vmcnt(12)). asm volatile
// loads cannot be collapsed by the scheduler (the R2 failure mode).
__global__ __launch_bounds__(256) void gcn_kernel(
        const float* __restrict__ adj, const unsigned short* __restrict__ supT,
        const float* __restrict__ bias, float* __restrict__ out) {
    const int t = threadIdx.x;
    const int l = t & 63;
    const int w = t >> 6;                    // 0..3 -> col group
    const int row0 = blockIdx.x * 16;

    // per-lane byte offsets (32-bit voffset, SGPR base)
    unsigned int aoff = (unsigned)(row0 + (l & 15)) * (N_NODES * 4)
                      + ((l >> 4) * 32);                 // 8 floats of k
    unsigned int boff0 = (unsigned)(w * 32 + (l & 15)) * (N_NODES * 2)
                       + ((l >> 4) * 16);                // 8 bf16 of k
    unsigned int boff1 = boff0 + 16u * (N_NODES * 2);

    f32x4 acc0 = {0.f,0.f,0.f,0.f}, acc1 = {0.f,0.f,0.f,0.f};

    // 4 named pipeline sets: Axy = fp32 lo/hi, Bxy = two B rows
    f32x4 a0L, a0H, a1L, a1H, a2L, a2H, a3L, a3H;
    u32x4 b0P, b0Q, b1P, b1Q, b2P, b2Q, b3P, b3Q;

#define PK(dst, a, b) \
    asm("v_cvt_pk_bf16_f32 %0, %1, %2" : "=v"(dst) : "v"(a), "v"(b))

#define LDA(dst, off, imm) \
    asm volatile("global_load_dwordx4 %0, %1, %2 offset:" imm \
                 : "=v"(dst) : "v"(off), "s"(adj) : "memory")
#define LDB(dst, off, imm) \
    asm volatile("global_load_dwordx4 %0, %1, %2 offset:" imm \
                 : "=v"(dst) : "v"(off), "s"(supT) : "memory")

// issue one step's 4 loads (order: A-lo, A-hi, B0, B1)
#define ISSUE(rAL, rAH, rBP, rBQ, AIMM, AIMM16, BIMM) { \
    LDA(rAL, aoff, AIMM); \
    LDA(rAH, aoff, AIMM16); \
    LDB(rBP, boff0, BIMM); \
    LDB(rBQ, boff1, BIMM); }

#define WAIT(IMM) { \
    asm volatile("s_waitcnt vmcnt(" IMM ")" ::: "memory"); \
    __builtin_amdgcn_sched_barrier(0); }

// consume one set; optionally re-issue same set for step s+4 (imm 512/528/256)
#define BODY(rAL, rAH, rBP, rBQ, WIMM, DO_ISSUE) { \
    WAIT(WIMM); \
    u32x4 q; \
    PK(q.x, rAL.x, rAL.y); PK(q.y, rAL.z, rAL.w); \
    PK(q.z, rAH.x, rAH.y); PK(q.w, rAH.z, rAH.w); \
    bf16x8 am = __builtin_bit_cast(bf16x8, q); \
    acc0 = __builtin_amdgcn_mfma_f32_16x16x32_bf16( \
        am, __builtin_bit_cast(bf16x8, rBP), acc0, 0, 0, 0); \
    acc1 = __builtin_amdgcn_mfma_f32_16x16x32_bf16( \
        am, __builtin_bit_cast(bf16x8, rBQ), acc1, 0, 0, 0); \
    if (DO_ISSUE) { \
        ISSUE(rAL, rAH, rBP, rBQ, "512", "528", "256"); \
        aoff += 128; boff0 += 64; boff1 += 64; \
    } }

    // prologue: issue steps 0..3 into sets 0..3 (16 loads in flight)
    ISSUE(a0L, a0H, b0P, b0Q, "0",   "16",  "0");
    ISSUE(a1L, a1H, b1P, b1Q, "128", "144", "64");
    ISSUE(a2L, a2H, b2P, b2Q, "256", "272", "128");
    ISSUE(a3L, a3H, b3P, b3Q, "384", "400", "192");

    // main: steps 0..251 (63 groups of 4); each body re-issues step s+4
    for (int g = 0; g < (NSTEP - 4) / 4; ++g) {
        BODY(a0L, a0H, b0P, b0Q, "12", 1);
        BODY(a1L, a1H, b1P, b1Q, "12", 1);
        BODY(a2L, a2H, b2P, b2Q, "12", 1);
        BODY(a3L, a3H, b3P, b3Q, "12", 1);
    }
    // tail: steps 252..255, drain 12 -> 8 -> 4 -> 0
    BODY(a0L, a0H, b0P, b0Q, "12", 0);
    BODY(a1L, a1H, b1P, b1Q, "8",  0);
    BODY(a2L, a2H, b2P, b2Q, "4",  0);
    BODY(a3L, a3H, b3P, b3Q, "0",  0);

#undef BODY
#undef WAIT
#undef ISSUE
#undef LDA
#undef LDB
#undef PK

    // epilogue: C/D layout col = l&15, row = (l>>4)*4 + i; direct store + bias
    const int col0 = w * 32 + (l & 15);
    const int r0 = row0 + (l >> 4) * 4;
    const float bv0 = bias[col0];
    const float bv1 = bias[col0 + 16];
    #pragma unroll
    for (int i = 0; i < 4; ++i) {
        float* o = out + (size_t)(r0 + i) * F_OUT + col0;
        o[0]  = acc0[i] + bv0;
        o[16] = acc1[i] + bv1;
    }
}

extern "C" void kernel_launch(void* const* d_in, const int* in_sizes, int n_in,
                              void* d_out, int out_size, void* d_ws, size_t ws_size,
                              hipStream_t stream) {
    const float* input  = (const float*)d_in[0];
    const float* adj    = (const float*)d_in[1];
    const float* weight = (const float*)d_in[2];
    const float* bias   = (const float*)d_in[3];
    float* out = (float*)d_out;
    unsigned short* supT = (unsigned short*)d_ws;           // 2 MiB

    support_kernel<<<N_NODES / 32, 256, 0, stream>>>(input, weight, supT);
    gcn_kernel<<<N_NODES / 16, 256, 0, stream>>>(adj, supT, bias, out);
}